// Round 14
// baseline (178.279 us; speedup 1.0000x reference)
//
#include <hip/hip_runtime.h>

#define D 64
#define K 1024
#define NROWS (32 * 4096)
#define NELEM (NROWS * D)
#define COMMIT 0.25f
#define DELTA 6e-5f

typedef __attribute__((ext_vector_type(8))) short short8v;   // 8 bf16
typedef __attribute__((ext_vector_type(4))) float f32x4;
typedef unsigned long long u64;

#define FORSLOT(M) M(0) M(1) M(2) M(3) M(4) M(5) M(6) M(7) \
                   M(8) M(9) M(10) M(11) M(12) M(13) M(14) M(15)

static __device__ __forceinline__ float fence(float v) {
    asm("" : "+v"(v));
    return v;
}

// f32 -> bf16 bits, round-to-nearest-even (finite inputs only).
static __device__ __forceinline__ unsigned short f2bf(float f) {
    unsigned u = __float_as_uint(f);
    return (unsigned short)((u + 0x7FFFu + ((u >> 16) & 1u)) >> 16);
}

// numpy pairwise_sum for n=64: 8 accumulators stride 8, then pairwise tree.
static __device__ __forceinline__ float np_sumsq64(const float* __restrict__ e) {
    float r[8];
#pragma unroll
    for (int j = 0; j < 8; ++j) r[j] = fence(e[j] * e[j]);
#pragma unroll
    for (int t = 1; t < 8; ++t)
#pragma unroll
        for (int j = 0; j < 8; ++j) r[j] = r[j] + fence(e[8 * t + j] * e[8 * t + j]);
    return ((r[0] + r[1]) + (r[2] + r[3])) + ((r[4] + r[5]) + (r[6] + r[7]));
}

// Bit-exact reference score: s = fl( fl(R+N) - 2*dot ), dot = ascending-i
// sequential FMA chain (validated absmax=0 in R2..R13).
static __device__ __forceinline__ float exact_score(
    const float* __restrict__ xrow, const float* __restrict__ erow, float R,
    float N) {
    float a = 0.0f;
#pragma unroll
    for (int i = 0; i < D; ++i) a = __builtin_fmaf(xrow[i], erow[i], a);
    return (R + N) - 2.0f * a;
}

// ---------------- Kernel 1: embedding prep ----------------
__global__ void prep_emb_kernel(const float* __restrict__ emb,
                                float* __restrict__ enorm,
                                unsigned short* __restrict__ e_hi,
                                unsigned short* __restrict__ e_lo,
                                float* __restrict__ loss_slot) {
    int k = blockIdx.x * blockDim.x + threadIdx.x;
    if (k == 0) *loss_slot = 0.0f;
    if (k >= K) return;
    enorm[k] = np_sumsq64(emb + k * D);
    const float* e = emb + k * D;
#pragma unroll
    for (int i = 0; i < D; ++i) {
        float v = e[i];
        unsigned short h = f2bf(v);
        float hf = __uint_as_float((unsigned)h << 16);
        e_hi[k * D + i] = h;
        e_lo[k * D + i] = f2bf(v - hf);  // v-hf exact (Sterbenz)
    }
}

// ---------------- Kernel 2: 2-pass MFMA argmin (R13 algorithm) --------------
// ONLY change vs R13: __launch_bounds__(256, 3). R13 counters (VGPR=88 arch
// regs, Occupancy 22% ~= 2 waves/SIMD) imply the unified-file AGPR usage
// pushed true per-wave regs past 128 -> residency-capped latency stalls.
// (256,3) makes the allocator fit ~170 combined regs -> 3 waves/SIMD.
__global__ __launch_bounds__(256, 3) void argmin_kernel(
    const float* __restrict__ x, const float* __restrict__ emb,
    const float* __restrict__ enorm, const unsigned short* __restrict__ e_hi,
    const unsigned short* __restrict__ e_lo, float* __restrict__ out_q,
    float* __restrict__ idx_f, float* __restrict__ loss_slot) {
    const int l = threadIdx.x & 63;
    const int w = threadIdx.x >> 6;
    const int rowbase = blockIdx.x * 64;
    const int cbase = w * 256;

    __shared__ float wminA[4][64];
    __shared__ float gmin[64];
    __shared__ int cnt[64];
    __shared__ int clist[64][8];
    __shared__ int bidx[64];
    __shared__ float wsum[4];

    // ---- A-fragments: named SSA short8v (validated R10-R13).
    // A layout (16x16x32): row = l&15, k = h*32 + (l>>4)*8 + i; B uses the
    // same per-lane k-permutation.
#define MKELT(hi, lo, i, v)                                                 \
    { unsigned short hb = f2bf(v);                                          \
      hi[i] = (short)hb;                                                    \
      lo[i] = (short)f2bf((v) - __uint_as_float((unsigned)hb << 16)); }
#define DECL_A(rt, h)                                                       \
    short8v Ahi_##rt##_##h, Alo_##rt##_##h;                                 \
    { const float* p = x + (size_t)(rowbase + rt * 16 + (l & 15)) * D +     \
                       h * 32 + (l >> 4) * 8;                               \
      float4 q0 = *(const float4*)p, q1 = *(const float4*)(p + 4);          \
      MKELT(Ahi_##rt##_##h, Alo_##rt##_##h, 0, q0.x)                        \
      MKELT(Ahi_##rt##_##h, Alo_##rt##_##h, 1, q0.y)                        \
      MKELT(Ahi_##rt##_##h, Alo_##rt##_##h, 2, q0.z)                        \
      MKELT(Ahi_##rt##_##h, Alo_##rt##_##h, 3, q0.w)                        \
      MKELT(Ahi_##rt##_##h, Alo_##rt##_##h, 4, q1.x)                        \
      MKELT(Ahi_##rt##_##h, Alo_##rt##_##h, 5, q1.y)                        \
      MKELT(Ahi_##rt##_##h, Alo_##rt##_##h, 6, q1.z)                        \
      MKELT(Ahi_##rt##_##h, Alo_##rt##_##h, 7, q1.w) }
    DECL_A(0, 0) DECL_A(0, 1) DECL_A(1, 0) DECL_A(1, 1)
    DECL_A(2, 0) DECL_A(2, 1) DECL_A(3, 0) DECL_A(3, 1)

    const int koff = (l >> 4) * 8;
    const size_t b0 = (size_t)(cbase + (l & 15)) * D + koff;

    // slot s = rt*4 + r maps to row (s/4)*16 + (l>>4)*4 + (s%4)
#define SLOTROW(s) (((s) / 4) * 16 + (l >> 4) * 4 + ((s) % 4))

    // =================== PASS A: fminf min ===================
#define DECL_MA(s) float mA_##s = 3.402823466e+38f;
    FORSLOT(DECL_MA)
    {
        const unsigned short* ph = e_hi + b0;
        const unsigned short* pl = e_lo + b0;
        const float* pe = enorm + cbase + (l & 15);
        short8v cH0 = *(const short8v*)ph;
        short8v cH1 = *(const short8v*)(ph + 32);
        short8v cL0 = *(const short8v*)pl;
        short8v cL1 = *(const short8v*)(pl + 32);
        float cNc = *pe;
#define MFMA6A(rt, sA, sB, sC, sD)                                          \
    { f32x4 acc = {0.f, 0.f, 0.f, 0.f};                                     \
      acc = __builtin_amdgcn_mfma_f32_16x16x32_bf16(Ahi_##rt##_0, Bhi0, acc, 0, 0, 0); \
      acc = __builtin_amdgcn_mfma_f32_16x16x32_bf16(Ahi_##rt##_1, Bhi1, acc, 0, 0, 0); \
      acc = __builtin_amdgcn_mfma_f32_16x16x32_bf16(Ahi_##rt##_0, Blo0, acc, 0, 0, 0); \
      acc = __builtin_amdgcn_mfma_f32_16x16x32_bf16(Ahi_##rt##_1, Blo1, acc, 0, 0, 0); \
      acc = __builtin_amdgcn_mfma_f32_16x16x32_bf16(Alo_##rt##_0, Bhi0, acc, 0, 0, 0); \
      acc = __builtin_amdgcn_mfma_f32_16x16x32_bf16(Alo_##rt##_1, Bhi1, acc, 0, 0, 0); \
      mA_##sA = fminf(mA_##sA, __builtin_fmaf(-2.0f, acc[0], Nc));          \
      mA_##sB = fminf(mA_##sB, __builtin_fmaf(-2.0f, acc[1], Nc));          \
      mA_##sC = fminf(mA_##sC, __builtin_fmaf(-2.0f, acc[2], Nc));          \
      mA_##sD = fminf(mA_##sD, __builtin_fmaf(-2.0f, acc[3], Nc)); }
        for (int nt = 0; nt < 16; ++nt) {
            short8v Bhi0 = cH0, Bhi1 = cH1, Blo0 = cL0, Blo1 = cL1;
            float Nc = cNc;
            if (nt < 15) {  // prefetch next tile (uniform branch)
                ph += 1024; pl += 1024; pe += 16;
                cH0 = *(const short8v*)ph;
                cH1 = *(const short8v*)(ph + 32);
                cL0 = *(const short8v*)pl;
                cL1 = *(const short8v*)(pl + 32);
                cNc = *pe;
            }
            MFMA6A(0, 0, 1, 2, 3)
            MFMA6A(1, 4, 5, 6, 7)
            MFMA6A(2, 8, 9, 10, 11)
            MFMA6A(3, 12, 13, 14, 15)
        }
    }
    // C/D layout: col = l&15 (code), row-group = 16 contiguous lanes.
#define BFA(s)                                                              \
    mA_##s = fminf(mA_##s, __shfl_xor(mA_##s, 1));                          \
    mA_##s = fminf(mA_##s, __shfl_xor(mA_##s, 2));                          \
    mA_##s = fminf(mA_##s, __shfl_xor(mA_##s, 4));                          \
    mA_##s = fminf(mA_##s, __shfl_xor(mA_##s, 8));
    FORSLOT(BFA)
#define WRA(s) if ((l & 15) == 0) wminA[w][SLOTROW(s)] = mA_##s;
    FORSLOT(WRA)
    __syncthreads();
    if (threadIdx.x < 64) {
        gmin[threadIdx.x] =
            fminf(fminf(wminA[0][threadIdx.x], wminA[1][threadIdx.x]),
                  fminf(wminA[2][threadIdx.x], wminA[3][threadIdx.x]));
        cnt[threadIdx.x] = 0;
    }
    __syncthreads();

    // =================== PASS B: candidate collection ===================
#define DECL_T(s) const float thr_##s = gmin[SLOTROW(s)] + DELTA;
    FORSLOT(DECL_T)
    {
        const unsigned short* ph = e_hi + b0;
        const unsigned short* pl = e_lo + b0;
        const float* pe = enorm + cbase + (l & 15);
        short8v cH0 = *(const short8v*)ph;
        short8v cH1 = *(const short8v*)(ph + 32);
        short8v cL0 = *(const short8v*)pl;
        short8v cL1 = *(const short8v*)(pl + 32);
        float cNc = *pe;
#define CHK(s, tval)                                                        \
    { float t = __builtin_fmaf(-2.0f, (tval), Nc);                          \
      if (t <= thr_##s) {                                                   \
          int row = SLOTROW(s);                                             \
          int pos = atomicAdd(&cnt[row], 1);                                \
          if (pos < 8) clist[row][pos] = code;                              \
      } }
#define MFMA6B(rt, sA, sB, sC, sD)                                          \
    { f32x4 acc = {0.f, 0.f, 0.f, 0.f};                                     \
      acc = __builtin_amdgcn_mfma_f32_16x16x32_bf16(Ahi_##rt##_0, Bhi0, acc, 0, 0, 0); \
      acc = __builtin_amdgcn_mfma_f32_16x16x32_bf16(Ahi_##rt##_1, Bhi1, acc, 0, 0, 0); \
      acc = __builtin_amdgcn_mfma_f32_16x16x32_bf16(Ahi_##rt##_0, Blo0, acc, 0, 0, 0); \
      acc = __builtin_amdgcn_mfma_f32_16x16x32_bf16(Ahi_##rt##_1, Blo1, acc, 0, 0, 0); \
      acc = __builtin_amdgcn_mfma_f32_16x16x32_bf16(Alo_##rt##_0, Bhi0, acc, 0, 0, 0); \
      acc = __builtin_amdgcn_mfma_f32_16x16x32_bf16(Alo_##rt##_1, Bhi1, acc, 0, 0, 0); \
      CHK(sA, acc[0]) CHK(sB, acc[1]) CHK(sC, acc[2]) CHK(sD, acc[3]) }
        int code = cbase + (l & 15);
        for (int nt = 0; nt < 16; ++nt) {
            short8v Bhi0 = cH0, Bhi1 = cH1, Blo0 = cL0, Blo1 = cL1;
            float Nc = cNc;
            if (nt < 15) {
                ph += 1024; pl += 1024; pe += 16;
                cH0 = *(const short8v*)ph;
                cH1 = *(const short8v*)(ph + 32);
                cL0 = *(const short8v*)pl;
                cL1 = *(const short8v*)(pl + 32);
                cNc = *pe;
            }
            MFMA6B(0, 0, 1, 2, 3)
            MFMA6B(1, 4, 5, 6, 7)
            MFMA6B(2, 8, 9, 10, 11)
            MFMA6B(3, 12, 13, 14, 15)
            code += 16;
        }
    }
    __syncthreads();

    // ---- select / rescue (1 thread per row) ----
    if (threadIdx.x < 64) {
        const int row = threadIdx.x;
        const int n = cnt[row];
        int bk;
        if (n == 1) {
            bk = clist[row][0];
        } else {
            const float* xrow = x + (size_t)(rowbase + row) * D;
            const float R = np_sumsq64(xrow);
            float sb = 3.402823466e+38f;
            int kb = 0x7fffffff;
            if (n <= 8) {
                for (int i = 0; i < n; ++i) {
                    int c = clist[row][i];
                    float s = exact_score(xrow, emb + ((size_t)c << 6), R,
                                          enorm[c]);
                    if (s < sb || (s == sb && c < kb)) { sb = s; kb = c; }
                }
            } else {  // clist overflow: full exact scan (essentially never)
                for (int c = 0; c < K; ++c) {
                    float s = exact_score(xrow, emb + ((size_t)c << 6), R,
                                          enorm[c]);
                    if (s < sb || (s == sb && c < kb)) { sb = s; kb = c; }
                }
            }
            bk = kb;
        }
        bidx[row] = bk;
        idx_f[rowbase + row] = (float)bk;
    }
    __syncthreads();

    // ---- fused epilogue: gather + straight-through + loss ----
    {
        const int row = threadIdx.x >> 2;
        const int d0 = (threadIdx.x & 3) * 16;
        const int bk = bidx[row];
        const float4* xq = (const float4*)(x + (size_t)(rowbase + row) * D + d0);
        const float4* eq = (const float4*)(emb + ((size_t)bk << 6) + d0);
        float4* oq = (float4*)(out_q + (size_t)(rowbase + row) * D + d0);
        float lsum = 0.f;
#pragma unroll
        for (int i = 0; i < 4; ++i) {
            float4 xv = xq[i];
            float4 ev = eq[i];
            float dx = ev.x - xv.x, dy = ev.y - xv.y, dz = ev.z - xv.z,
                  dw = ev.w - xv.w;
            float4 o;
            o.x = xv.x + dx;
            o.y = xv.y + dy;
            o.z = xv.z + dz;
            o.w = xv.w + dw;
            oq[i] = o;
            lsum = __builtin_fmaf(dx, dx, lsum);
            lsum = __builtin_fmaf(dy, dy, lsum);
            lsum = __builtin_fmaf(dz, dz, lsum);
            lsum = __builtin_fmaf(dw, dw, lsum);
        }
#pragma unroll
        for (int o = 32; o > 0; o >>= 1) lsum += __shfl_xor(lsum, o);
        if (l == 0) wsum[w] = lsum;
        __syncthreads();
        if (threadIdx.x == 0)
            atomicAdd(loss_slot, ((wsum[0] + wsum[1]) + (wsum[2] + wsum[3])) *
                                     ((1.0f + COMMIT) / (float)NELEM));
    }
}

extern "C" void kernel_launch(void* const* d_in, const int* in_sizes, int n_in,
                              void* d_out, int out_size, void* d_ws,
                              size_t ws_size, hipStream_t stream) {
    const float* x = (const float*)d_in[0];    // [32,4096,64] f32
    const float* emb = (const float*)d_in[1];  // [1024,64] f32

    float* out = (float*)d_out;
    float* loss_slot = out;              // out[0]
    float* out_q = out + 1;              // out[1 .. 1+NELEM)
    float* idx_f = out + 1 + NELEM;      // indices as f32

    // workspace layout (16B-aligned slabs)
    float* enorm = (float*)d_ws;                                    // 4 KB
    unsigned short* e_hi = (unsigned short*)((char*)d_ws + 4096);   // 128 KB
    unsigned short* e_lo = (unsigned short*)((char*)d_ws + 135168); // 128 KB

    prep_emb_kernel<<<(K + 255) / 256, 256, 0, stream>>>(emb, enorm, e_hi,
                                                         e_lo, loss_slot);
    argmin_kernel<<<NROWS / 64, 256, 0, stream>>>(x, emb, enorm, e_hi, e_lo,
                                                  out_q, idx_f, loss_slot);
}

// Round 15
// 162.224 us; speedup vs baseline: 1.0990x; 1.0990x over previous
//
#include <hip/hip_runtime.h>

#define D 64
#define K 1024
#define NROWS (32 * 4096)
#define NELEM (NROWS * D)
#define COMMIT 0.25f
#define DELTA 6e-5f

typedef __attribute__((ext_vector_type(8))) short short8v;   // 8 bf16
typedef __attribute__((ext_vector_type(4))) float f32x4;
typedef unsigned long long u64;

#define FORSLOT(M) M(0) M(1) M(2) M(3) M(4) M(5) M(6) M(7) \
                   M(8) M(9) M(10) M(11) M(12) M(13) M(14) M(15)

static __device__ __forceinline__ float fence(float v) {
    asm("" : "+v"(v));
    return v;
}

// f32 -> bf16 bits, round-to-nearest-even (finite inputs only).
static __device__ __forceinline__ unsigned short f2bf(float f) {
    unsigned u = __float_as_uint(f);
    return (unsigned short)((u + 0x7FFFu + ((u >> 16) & 1u)) >> 16);
}

// numpy pairwise_sum for n=64: 8 accumulators stride 8, then pairwise tree.
static __device__ __forceinline__ float np_sumsq64(const float* __restrict__ e) {
    float r[8];
#pragma unroll
    for (int j = 0; j < 8; ++j) r[j] = fence(e[j] * e[j]);
#pragma unroll
    for (int t = 1; t < 8; ++t)
#pragma unroll
        for (int j = 0; j < 8; ++j) r[j] = r[j] + fence(e[8 * t + j] * e[8 * t + j]);
    return ((r[0] + r[1]) + (r[2] + r[3])) + ((r[4] + r[5]) + (r[6] + r[7]));
}

// Bit-exact reference score: s = fl( fl(R+N) - 2*dot ), dot = ascending-i
// sequential FMA chain (validated absmax=0 in R2..R14).
static __device__ __forceinline__ float exact_score(
    const float* __restrict__ xrow, const float* __restrict__ erow, float R,
    float N) {
    float a = 0.0f;
#pragma unroll
    for (int i = 0; i < D; ++i) a = __builtin_fmaf(xrow[i], erow[i], a);
    return (R + N) - 2.0f * a;
}

// ---------------- Kernel 1: embedding prep ----------------
__global__ void prep_emb_kernel(const float* __restrict__ emb,
                                float* __restrict__ enorm,
                                unsigned short* __restrict__ e_hi,
                                unsigned short* __restrict__ e_lo,
                                float* __restrict__ loss_slot) {
    int k = blockIdx.x * blockDim.x + threadIdx.x;
    if (k == 0) *loss_slot = 0.0f;
    if (k >= K) return;
    enorm[k] = np_sumsq64(emb + k * D);
    const float* e = emb + k * D;
#pragma unroll
    for (int i = 0; i < D; ++i) {
        float v = e[i];
        unsigned short h = f2bf(v);
        float hf = __uint_as_float((unsigned)h << 16);
        e_hi[k * D + i] = h;
        e_lo[k * D + i] = f2bf(v - hf);  // v-hf exact (Sterbenz)
    }
}

// ---------------- Kernel 2: 2-pass MFMA argmin, PING-PONG pipelined ---------
// R13 algorithm (absmax=0), one structural change: the nt-loops use true
// double buffering with DISTINCT named register sets (A/B), unrolled x2.
// R13/R14's rotate-by-copy prefetch had a WAR hazard after copy-coalescing:
// the refill loads targeted the same regs the in-flight MFMAs read, so loads
// serialized behind compute and L2 latency (~250cyc/nt) was exposed
// (MfmaUtil 25%). Ping-pong lets loads issue a full tile (~460cyc) early.
// Occupancy is register-class-capped at 2 waves/SIMD (R14: forcing 3 spills
// 16MB to scratch), so ILP -- not TLP -- must hide latency.
__global__ __launch_bounds__(256, 1) void argmin_kernel(
    const float* __restrict__ x, const float* __restrict__ emb,
    const float* __restrict__ enorm, const unsigned short* __restrict__ e_hi,
    const unsigned short* __restrict__ e_lo, float* __restrict__ out_q,
    float* __restrict__ idx_f, float* __restrict__ loss_slot) {
    const int l = threadIdx.x & 63;
    const int w = threadIdx.x >> 6;
    const int rowbase = blockIdx.x * 64;
    const int cbase = w * 256;

    __shared__ float wminA[4][64];
    __shared__ float gmin[64];
    __shared__ int cnt[64];
    __shared__ int clist[64][8];
    __shared__ int bidx[64];
    __shared__ float wsum[4];

    // ---- A-fragments: named SSA short8v (validated R10-R14).
    // A layout (16x16x32): row = l&15, k = h*32 + (l>>4)*8 + i; B uses the
    // same per-lane k-permutation.
#define MKELT(hi, lo, i, v)                                                 \
    { unsigned short hb = f2bf(v);                                          \
      hi[i] = (short)hb;                                                    \
      lo[i] = (short)f2bf((v) - __uint_as_float((unsigned)hb << 16)); }
#define DECL_A(rt, h)                                                       \
    short8v Ahi_##rt##_##h, Alo_##rt##_##h;                                 \
    { const float* p = x + (size_t)(rowbase + rt * 16 + (l & 15)) * D +     \
                       h * 32 + (l >> 4) * 8;                               \
      float4 q0 = *(const float4*)p, q1 = *(const float4*)(p + 4);          \
      MKELT(Ahi_##rt##_##h, Alo_##rt##_##h, 0, q0.x)                        \
      MKELT(Ahi_##rt##_##h, Alo_##rt##_##h, 1, q0.y)                        \
      MKELT(Ahi_##rt##_##h, Alo_##rt##_##h, 2, q0.z)                        \
      MKELT(Ahi_##rt##_##h, Alo_##rt##_##h, 3, q0.w)                        \
      MKELT(Ahi_##rt##_##h, Alo_##rt##_##h, 4, q1.x)                        \
      MKELT(Ahi_##rt##_##h, Alo_##rt##_##h, 5, q1.y)                        \
      MKELT(Ahi_##rt##_##h, Alo_##rt##_##h, 6, q1.z)                        \
      MKELT(Ahi_##rt##_##h, Alo_##rt##_##h, 7, q1.w) }
    DECL_A(0, 0) DECL_A(0, 1) DECL_A(1, 0) DECL_A(1, 1)
    DECL_A(2, 0) DECL_A(2, 1) DECL_A(3, 0) DECL_A(3, 1)

    const int koff = (l >> 4) * 8;
    const unsigned short* __restrict__ bh = e_hi + (size_t)(cbase + (l & 15)) * D + koff;
    const unsigned short* __restrict__ bl = e_lo + (size_t)(cbase + (l & 15)) * D + koff;
    const float* __restrict__ bn = enorm + cbase + (l & 15);

#define LOADT(H0, H1, L0, L1, NN, off)                                      \
    H0 = *(const short8v*)(bh + (off) * 1024);                              \
    H1 = *(const short8v*)(bh + (off) * 1024 + 32);                         \
    L0 = *(const short8v*)(bl + (off) * 1024);                              \
    L1 = *(const short8v*)(bl + (off) * 1024 + 32);                         \
    NN = bn[(off) * 16];

    // slot s = rt*4 + r maps to row (s/4)*16 + (l>>4)*4 + (s%4)
#define SLOTROW(s) (((s) / 4) * 16 + (l >> 4) * 4 + ((s) % 4))

    // =================== PASS A: fminf min, ping-pong ===================
#define DECL_MA(s) float mA_##s = 3.402823466e+38f;
    FORSLOT(DECL_MA)
#define MFMA6A(rt, sA, sB, sC, sD)                                          \
    { f32x4 acc = {0.f, 0.f, 0.f, 0.f};                                     \
      acc = __builtin_amdgcn_mfma_f32_16x16x32_bf16(Ahi_##rt##_0, Bhi0, acc, 0, 0, 0); \
      acc = __builtin_amdgcn_mfma_f32_16x16x32_bf16(Ahi_##rt##_1, Bhi1, acc, 0, 0, 0); \
      acc = __builtin_amdgcn_mfma_f32_16x16x32_bf16(Ahi_##rt##_0, Blo0, acc, 0, 0, 0); \
      acc = __builtin_amdgcn_mfma_f32_16x16x32_bf16(Ahi_##rt##_1, Blo1, acc, 0, 0, 0); \
      acc = __builtin_amdgcn_mfma_f32_16x16x32_bf16(Alo_##rt##_0, Bhi0, acc, 0, 0, 0); \
      acc = __builtin_amdgcn_mfma_f32_16x16x32_bf16(Alo_##rt##_1, Bhi1, acc, 0, 0, 0); \
      mA_##sA = fminf(mA_##sA, __builtin_fmaf(-2.0f, acc[0], Nc));          \
      mA_##sB = fminf(mA_##sB, __builtin_fmaf(-2.0f, acc[1], Nc));          \
      mA_##sC = fminf(mA_##sC, __builtin_fmaf(-2.0f, acc[2], Nc));          \
      mA_##sD = fminf(mA_##sD, __builtin_fmaf(-2.0f, acc[3], Nc)); }
#define TILEA(H0, H1, L0, L1, NN)                                           \
    { const short8v Bhi0 = H0, Bhi1 = H1, Blo0 = L0, Blo1 = L1;             \
      const float Nc = NN;                                                  \
      MFMA6A(0, 0, 1, 2, 3) MFMA6A(1, 4, 5, 6, 7)                           \
      MFMA6A(2, 8, 9, 10, 11) MFMA6A(3, 12, 13, 14, 15) }
    {
        short8v pH0, pH1, pL0, pL1;  // ping buffer
        short8v qH0, qH1, qL0, qL1;  // pong buffer
        float pN, qN;
        LOADT(pH0, pH1, pL0, pL1, pN, 0)
        for (int nt = 0; nt < 16; nt += 2) {
            LOADT(qH0, qH1, qL0, qL1, qN, nt + 1)          // prefetch odd
            TILEA(pH0, pH1, pL0, pL1, pN)                  // compute even
            const int nxt = (nt + 2 < 16) ? nt + 2 : 15;   // clamp (unused)
            LOADT(pH0, pH1, pL0, pL1, pN, nxt)             // prefetch even
            TILEA(qH0, qH1, qL0, qL1, qN)                  // compute odd
        }
    }
    // C/D layout: col = l&15 (code), row-group = 16 contiguous lanes.
#define BFA(s)                                                              \
    mA_##s = fminf(mA_##s, __shfl_xor(mA_##s, 1));                          \
    mA_##s = fminf(mA_##s, __shfl_xor(mA_##s, 2));                          \
    mA_##s = fminf(mA_##s, __shfl_xor(mA_##s, 4));                          \
    mA_##s = fminf(mA_##s, __shfl_xor(mA_##s, 8));
    FORSLOT(BFA)
#define WRA(s) if ((l & 15) == 0) wminA[w][SLOTROW(s)] = mA_##s;
    FORSLOT(WRA)
    __syncthreads();
    if (threadIdx.x < 64) {
        gmin[threadIdx.x] =
            fminf(fminf(wminA[0][threadIdx.x], wminA[1][threadIdx.x]),
                  fminf(wminA[2][threadIdx.x], wminA[3][threadIdx.x]));
        cnt[threadIdx.x] = 0;
    }
    __syncthreads();

    // =================== PASS B: candidate collection, ping-pong ============
#define DECL_T(s) const float thr_##s = gmin[SLOTROW(s)] + DELTA;
    FORSLOT(DECL_T)
#define CHK(s, tval)                                                        \
    { float t = __builtin_fmaf(-2.0f, (tval), Nc);                          \
      if (t <= thr_##s) {                                                   \
          int row = SLOTROW(s);                                             \
          int pos = atomicAdd(&cnt[row], 1);                                \
          if (pos < 8) clist[row][pos] = code;                              \
      } }
#define MFMA6B(rt, sA, sB, sC, sD)                                          \
    { f32x4 acc = {0.f, 0.f, 0.f, 0.f};                                     \
      acc = __builtin_amdgcn_mfma_f32_16x16x32_bf16(Ahi_##rt##_0, Bhi0, acc, 0, 0, 0); \
      acc = __builtin_amdgcn_mfma_f32_16x16x32_bf16(Ahi_##rt##_1, Bhi1, acc, 0, 0, 0); \
      acc = __builtin_amdgcn_mfma_f32_16x16x32_bf16(Ahi_##rt##_0, Blo0, acc, 0, 0, 0); \
      acc = __builtin_amdgcn_mfma_f32_16x16x32_bf16(Ahi_##rt##_1, Blo1, acc, 0, 0, 0); \
      acc = __builtin_amdgcn_mfma_f32_16x16x32_bf16(Alo_##rt##_0, Bhi0, acc, 0, 0, 0); \
      acc = __builtin_amdgcn_mfma_f32_16x16x32_bf16(Alo_##rt##_1, Bhi1, acc, 0, 0, 0); \
      CHK(sA, acc[0]) CHK(sB, acc[1]) CHK(sC, acc[2]) CHK(sD, acc[3]) }
#define TILEB(H0, H1, L0, L1, NN, NT)                                       \
    { const short8v Bhi0 = H0, Bhi1 = H1, Blo0 = L0, Blo1 = L1;             \
      const float Nc = NN;                                                  \
      const int code = cbase + (l & 15) + (NT) * 16;                        \
      MFMA6B(0, 0, 1, 2, 3) MFMA6B(1, 4, 5, 6, 7)                           \
      MFMA6B(2, 8, 9, 10, 11) MFMA6B(3, 12, 13, 14, 15) }
    {
        short8v pH0, pH1, pL0, pL1;
        short8v qH0, qH1, qL0, qL1;
        float pN, qN;
        LOADT(pH0, pH1, pL0, pL1, pN, 0)
        for (int nt = 0; nt < 16; nt += 2) {
            LOADT(qH0, qH1, qL0, qL1, qN, nt + 1)
            TILEB(pH0, pH1, pL0, pL1, pN, nt)
            const int nxt = (nt + 2 < 16) ? nt + 2 : 15;
            LOADT(pH0, pH1, pL0, pL1, pN, nxt)
            TILEB(qH0, qH1, qL0, qL1, qN, nt + 1)
        }
    }
    __syncthreads();

    // ---- select / rescue (1 thread per row) ----
    if (threadIdx.x < 64) {
        const int row = threadIdx.x;
        const int n = cnt[row];
        int bk;
        if (n == 1) {
            bk = clist[row][0];
        } else {
            const float* xrow = x + (size_t)(rowbase + row) * D;
            const float R = np_sumsq64(xrow);
            float sb = 3.402823466e+38f;
            int kb = 0x7fffffff;
            if (n <= 8) {
                for (int i = 0; i < n; ++i) {
                    int c = clist[row][i];
                    float s = exact_score(xrow, emb + ((size_t)c << 6), R,
                                          enorm[c]);
                    if (s < sb || (s == sb && c < kb)) { sb = s; kb = c; }
                }
            } else {  // clist overflow: full exact scan (essentially never)
                for (int c = 0; c < K; ++c) {
                    float s = exact_score(xrow, emb + ((size_t)c << 6), R,
                                          enorm[c]);
                    if (s < sb || (s == sb && c < kb)) { sb = s; kb = c; }
                }
            }
            bk = kb;
        }
        bidx[row] = bk;
        idx_f[rowbase + row] = (float)bk;
    }
    __syncthreads();

    // ---- fused epilogue: gather + straight-through + loss ----
    {
        const int row = threadIdx.x >> 2;
        const int d0 = (threadIdx.x & 3) * 16;
        const int bk = bidx[row];
        const float4* xq = (const float4*)(x + (size_t)(rowbase + row) * D + d0);
        const float4* eq = (const float4*)(emb + ((size_t)bk << 6) + d0);
        float4* oq = (float4*)(out_q + (size_t)(rowbase + row) * D + d0);
        float lsum = 0.f;
#pragma unroll
        for (int i = 0; i < 4; ++i) {
            float4 xv = xq[i];
            float4 ev = eq[i];
            float dx = ev.x - xv.x, dy = ev.y - xv.y, dz = ev.z - xv.z,
                  dw = ev.w - xv.w;
            float4 o;
            o.x = xv.x + dx;
            o.y = xv.y + dy;
            o.z = xv.z + dz;
            o.w = xv.w + dw;
            oq[i] = o;
            lsum = __builtin_fmaf(dx, dx, lsum);
            lsum = __builtin_fmaf(dy, dy, lsum);
            lsum = __builtin_fmaf(dz, dz, lsum);
            lsum = __builtin_fmaf(dw, dw, lsum);
        }
#pragma unroll
        for (int o = 32; o > 0; o >>= 1) lsum += __shfl_xor(lsum, o);
        if (l == 0) wsum[w] = lsum;
        __syncthreads();
        if (threadIdx.x == 0)
            atomicAdd(loss_slot, ((wsum[0] + wsum[1]) + (wsum[2] + wsum[3])) *
                                     ((1.0f + COMMIT) / (float)NELEM));
    }
}

extern "C" void kernel_launch(void* const* d_in, const int* in_sizes, int n_in,
                              void* d_out, int out_size, void* d_ws,
                              size_t ws_size, hipStream_t stream) {
    const float* x = (const float*)d_in[0];    // [32,4096,64] f32
    const float* emb = (const float*)d_in[1];  // [1024,64] f32

    float* out = (float*)d_out;
    float* loss_slot = out;              // out[0]
    float* out_q = out + 1;              // out[1 .. 1+NELEM)
    float* idx_f = out + 1 + NELEM;      // indices as f32

    // workspace layout (16B-aligned slabs)
    float* enorm = (float*)d_ws;                                    // 4 KB
    unsigned short* e_hi = (unsigned short*)((char*)d_ws + 4096);   // 128 KB
    unsigned short* e_lo = (unsigned short*)((char*)d_ws + 135168); // 128 KB

    prep_emb_kernel<<<(K + 255) / 256, 256, 0, stream>>>(emb, enorm, e_hi,
                                                         e_lo, loss_slot);
    argmin_kernel<<<NROWS / 64, 256, 0, stream>>>(x, emb, enorm, e_hi, e_lo,
                                                  out_q, idx_f, loss_slot);
}

// Round 16
// 109.857 us; speedup vs baseline: 1.6228x; 1.4767x over previous
//
#include <hip/hip_runtime.h>

#define D 64
#define K 1024
#define NROWS (32 * 4096)
#define NELEM (NROWS * D)
#define COMMIT 0.25f
#define DELTA 1.2e-4f

typedef __attribute__((ext_vector_type(8))) short short8v;   // 8 bf16
typedef __attribute__((ext_vector_type(4))) float f32x4;
typedef unsigned long long u64;

#define FORSLOT(M) M(0) M(1) M(2) M(3) M(4) M(5) M(6) M(7) \
                   M(8) M(9) M(10) M(11) M(12) M(13) M(14) M(15)

static __device__ __forceinline__ float fence(float v) {
    asm("" : "+v"(v));
    return v;
}

// f32 -> bf16 bits, round-to-nearest-even (finite inputs only).
static __device__ __forceinline__ unsigned short f2bf(float f) {
    unsigned u = __float_as_uint(f);
    return (unsigned short)((u + 0x7FFFu + ((u >> 16) & 1u)) >> 16);
}

// numpy pairwise_sum for n=64: 8 accumulators stride 8, then pairwise tree.
static __device__ __forceinline__ float np_sumsq64(const float* __restrict__ e) {
    float r[8];
#pragma unroll
    for (int j = 0; j < 8; ++j) r[j] = fence(e[j] * e[j]);
#pragma unroll
    for (int t = 1; t < 8; ++t)
#pragma unroll
        for (int j = 0; j < 8; ++j) r[j] = r[j] + fence(e[8 * t + j] * e[8 * t + j]);
    return ((r[0] + r[1]) + (r[2] + r[3])) + ((r[4] + r[5]) + (r[6] + r[7]));
}

// Bit-exact reference score: s = fl( fl(R+N) - 2*dot ), dot = ascending-i
// sequential FMA chain (validated absmax=0 in R2..R15).
static __device__ __forceinline__ float exact_score(
    const float* __restrict__ xrow, const float* __restrict__ erow, float R,
    float N) {
    float a = 0.0f;
#pragma unroll
    for (int i = 0; i < D; ++i) a = __builtin_fmaf(xrow[i], erow[i], a);
    return (R + N) - 2.0f * a;
}

// ---------------- Kernel 1: embedding prep (bf16 only, no lo table) ---------
__global__ void prep_emb_kernel(const float* __restrict__ emb,
                                float* __restrict__ enorm,
                                unsigned short* __restrict__ e_hi,
                                float* __restrict__ loss_slot) {
    int k = blockIdx.x * blockDim.x + threadIdx.x;
    if (k == 0) *loss_slot = 0.0f;
    if (k >= K) return;
    enorm[k] = np_sumsq64(emb + k * D);
    const float* e = emb + k * D;
#pragma unroll
    for (int i = 0; i < D; ++i) e_hi[k * D + i] = f2bf(e[i]);
}

// ---------------- Kernel 2: 2-pass single-product MFMA argmin ---------------
// t_k = N_k - 2*dot(bf16(x), bf16(e)). Error budget: e-rounding sigma~1e-6
// (|e|<2^-10 so bf16 e is ~exact); x-rounding enters code-vs-code comparisons
// only through dot(xl, e_i - e_j), sigma ~5e-6. Reference winner obeys
// t_{k*} <= t_min + ~4e-5; DELTA=1.2e-4 gives 18-sigma inclusion margin.
// Candidates re-scored with the bit-exact chain -> final answer exact.
// vs R15: 8 MFMA/tile (was 24), 2 B-loads (was 4), A-frags 32 VGPR (was 64),
// no e_lo. Pressure ~110 regs -> target 4 waves/SIMD (R14 proved old
// structure >170). Ping-pong B double-buffer kept.
__global__ __launch_bounds__(256, 1) void argmin_kernel(
    const float* __restrict__ x, const float* __restrict__ emb,
    const float* __restrict__ enorm, const unsigned short* __restrict__ e_hi,
    float* __restrict__ out_q, float* __restrict__ idx_f,
    float* __restrict__ loss_slot) {
    const int l = threadIdx.x & 63;
    const int w = threadIdx.x >> 6;
    const int rowbase = blockIdx.x * 64;
    const int cbase = w * 256;

    __shared__ float wminA[4][64];
    __shared__ float gmin[64];
    __shared__ int cnt[64];
    __shared__ int clist[64][8];
    __shared__ int bidx[64];
    __shared__ float wsum[4];

    // ---- A-fragments: bf16(x), named SSA short8v. Layout (16x16x32):
    // row = l&15, k = h*32 + (l>>4)*8 + i; B uses the same permutation.
#define DECL_A(rt, h)                                                       \
    short8v Ahi_##rt##_##h;                                                 \
    { const float* p = x + (size_t)(rowbase + rt * 16 + (l & 15)) * D +     \
                       h * 32 + (l >> 4) * 8;                               \
      float4 q0 = *(const float4*)p, q1 = *(const float4*)(p + 4);          \
      Ahi_##rt##_##h[0] = (short)f2bf(q0.x);                                \
      Ahi_##rt##_##h[1] = (short)f2bf(q0.y);                                \
      Ahi_##rt##_##h[2] = (short)f2bf(q0.z);                                \
      Ahi_##rt##_##h[3] = (short)f2bf(q0.w);                                \
      Ahi_##rt##_##h[4] = (short)f2bf(q1.x);                                \
      Ahi_##rt##_##h[5] = (short)f2bf(q1.y);                                \
      Ahi_##rt##_##h[6] = (short)f2bf(q1.z);                                \
      Ahi_##rt##_##h[7] = (short)f2bf(q1.w); }
    DECL_A(0, 0) DECL_A(0, 1) DECL_A(1, 0) DECL_A(1, 1)
    DECL_A(2, 0) DECL_A(2, 1) DECL_A(3, 0) DECL_A(3, 1)

    const int koff = (l >> 4) * 8;
    const unsigned short* __restrict__ bh =
        e_hi + (size_t)(cbase + (l & 15)) * D + koff;
    const float* __restrict__ bn = enorm + cbase + (l & 15);

#define LOADT(H0, H1, NN, off)                                              \
    H0 = *(const short8v*)(bh + (off) * 1024);                              \
    H1 = *(const short8v*)(bh + (off) * 1024 + 32);                         \
    NN = bn[(off) * 16];

    // slot s = rt*4 + r maps to row (s/4)*16 + (l>>4)*4 + (s%4)
#define SLOTROW(s) (((s) / 4) * 16 + (l >> 4) * 4 + ((s) % 4))

    // =================== PASS A: fminf min, ping-pong ===================
#define DECL_MA(s) float mA_##s = 3.402823466e+38f;
    FORSLOT(DECL_MA)
#define MFMA2A(rt, sA, sB, sC, sD)                                          \
    { f32x4 acc = {0.f, 0.f, 0.f, 0.f};                                     \
      acc = __builtin_amdgcn_mfma_f32_16x16x32_bf16(Ahi_##rt##_0, Bhi0, acc, 0, 0, 0); \
      acc = __builtin_amdgcn_mfma_f32_16x16x32_bf16(Ahi_##rt##_1, Bhi1, acc, 0, 0, 0); \
      mA_##sA = fminf(mA_##sA, __builtin_fmaf(-2.0f, acc[0], Nc));          \
      mA_##sB = fminf(mA_##sB, __builtin_fmaf(-2.0f, acc[1], Nc));          \
      mA_##sC = fminf(mA_##sC, __builtin_fmaf(-2.0f, acc[2], Nc));          \
      mA_##sD = fminf(mA_##sD, __builtin_fmaf(-2.0f, acc[3], Nc)); }
#define TILEA(H0, H1, NN)                                                   \
    { const short8v Bhi0 = H0, Bhi1 = H1;                                   \
      const float Nc = NN;                                                  \
      MFMA2A(0, 0, 1, 2, 3) MFMA2A(1, 4, 5, 6, 7)                           \
      MFMA2A(2, 8, 9, 10, 11) MFMA2A(3, 12, 13, 14, 15) }
    {
        short8v pH0, pH1, qH0, qH1;
        float pN, qN;
        LOADT(pH0, pH1, pN, 0)
        for (int nt = 0; nt < 16; nt += 2) {
            LOADT(qH0, qH1, qN, nt + 1)
            TILEA(pH0, pH1, pN)
            const int nxt = (nt + 2 < 16) ? nt + 2 : 15;
            LOADT(pH0, pH1, pN, nxt)
            TILEA(qH0, qH1, qN)
        }
    }
    // C/D layout: col = l&15 (code), row-group = 16 contiguous lanes.
#define BFA(s)                                                              \
    mA_##s = fminf(mA_##s, __shfl_xor(mA_##s, 1));                          \
    mA_##s = fminf(mA_##s, __shfl_xor(mA_##s, 2));                          \
    mA_##s = fminf(mA_##s, __shfl_xor(mA_##s, 4));                          \
    mA_##s = fminf(mA_##s, __shfl_xor(mA_##s, 8));
    FORSLOT(BFA)
#define WRA(s) if ((l & 15) == 0) wminA[w][SLOTROW(s)] = mA_##s;
    FORSLOT(WRA)
    __syncthreads();
    if (threadIdx.x < 64) {
        gmin[threadIdx.x] =
            fminf(fminf(wminA[0][threadIdx.x], wminA[1][threadIdx.x]),
                  fminf(wminA[2][threadIdx.x], wminA[3][threadIdx.x]));
        cnt[threadIdx.x] = 0;
    }
    __syncthreads();

    // =================== PASS B: candidate collection, ping-pong ============
#define DECL_T(s) const float thr_##s = gmin[SLOTROW(s)] + DELTA;
    FORSLOT(DECL_T)
#define CHK(s, tval)                                                        \
    { float t = __builtin_fmaf(-2.0f, (tval), Nc);                          \
      if (t <= thr_##s) {                                                   \
          int row = SLOTROW(s);                                             \
          int pos = atomicAdd(&cnt[row], 1);                                \
          if (pos < 8) clist[row][pos] = code;                              \
      } }
#define MFMA2B(rt, sA, sB, sC, sD)                                          \
    { f32x4 acc = {0.f, 0.f, 0.f, 0.f};                                     \
      acc = __builtin_amdgcn_mfma_f32_16x16x32_bf16(Ahi_##rt##_0, Bhi0, acc, 0, 0, 0); \
      acc = __builtin_amdgcn_mfma_f32_16x16x32_bf16(Ahi_##rt##_1, Bhi1, acc, 0, 0, 0); \
      CHK(sA, acc[0]) CHK(sB, acc[1]) CHK(sC, acc[2]) CHK(sD, acc[3]) }
#define TILEB(H0, H1, NN, NT)                                               \
    { const short8v Bhi0 = H0, Bhi1 = H1;                                   \
      const float Nc = NN;                                                  \
      const int code = cbase + (l & 15) + (NT) * 16;                        \
      MFMA2B(0, 0, 1, 2, 3) MFMA2B(1, 4, 5, 6, 7)                           \
      MFMA2B(2, 8, 9, 10, 11) MFMA2B(3, 12, 13, 14, 15) }
    {
        short8v pH0, pH1, qH0, qH1;
        float pN, qN;
        LOADT(pH0, pH1, pN, 0)
        for (int nt = 0; nt < 16; nt += 2) {
            LOADT(qH0, qH1, qN, nt + 1)
            TILEB(pH0, pH1, pN, nt)
            const int nxt = (nt + 2 < 16) ? nt + 2 : 15;
            LOADT(pH0, pH1, pN, nxt)
            TILEB(qH0, qH1, qN, nt + 1)
        }
    }
    __syncthreads();

    // ---- select / rescue (1 thread per row), bit-exact final answer ----
    if (threadIdx.x < 64) {
        const int row = threadIdx.x;
        const int n = cnt[row];
        int bk;
        if (n == 1) {
            bk = clist[row][0];
        } else {
            const float* xrow = x + (size_t)(rowbase + row) * D;
            const float R = np_sumsq64(xrow);
            float sb = 3.402823466e+38f;
            int kb = 0x7fffffff;
            if (n <= 8) {
                for (int i = 0; i < n; ++i) {
                    int c = clist[row][i];
                    float s = exact_score(xrow, emb + ((size_t)c << 6), R,
                                          enorm[c]);
                    if (s < sb || (s == sb && c < kb)) { sb = s; kb = c; }
                }
            } else {  // clist overflow: full exact scan (essentially never)
                for (int c = 0; c < K; ++c) {
                    float s = exact_score(xrow, emb + ((size_t)c << 6), R,
                                          enorm[c]);
                    if (s < sb || (s == sb && c < kb)) { sb = s; kb = c; }
                }
            }
            bk = kb;
        }
        bidx[row] = bk;
        idx_f[rowbase + row] = (float)bk;
    }
    __syncthreads();

    // ---- fused epilogue: gather + straight-through + loss ----
    {
        const int row = threadIdx.x >> 2;
        const int d0 = (threadIdx.x & 3) * 16;
        const int bk = bidx[row];
        const float4* xq = (const float4*)(x + (size_t)(rowbase + row) * D + d0);
        const float4* eq = (const float4*)(emb + ((size_t)bk << 6) + d0);
        float4* oq = (float4*)(out_q + (size_t)(rowbase + row) * D + d0);
        float lsum = 0.f;
#pragma unroll
        for (int i = 0; i < 4; ++i) {
            float4 xv = xq[i];
            float4 ev = eq[i];
            float dx = ev.x - xv.x, dy = ev.y - xv.y, dz = ev.z - xv.z,
                  dw = ev.w - xv.w;
            float4 o;
            o.x = xv.x + dx;
            o.y = xv.y + dy;
            o.z = xv.z + dz;
            o.w = xv.w + dw;
            oq[i] = o;
            lsum = __builtin_fmaf(dx, dx, lsum);
            lsum = __builtin_fmaf(dy, dy, lsum);
            lsum = __builtin_fmaf(dz, dz, lsum);
            lsum = __builtin_fmaf(dw, dw, lsum);
        }
#pragma unroll
        for (int o = 32; o > 0; o >>= 1) lsum += __shfl_xor(lsum, o);
        if (l == 0) wsum[w] = lsum;
        __syncthreads();
        if (threadIdx.x == 0)
            atomicAdd(loss_slot, ((wsum[0] + wsum[1]) + (wsum[2] + wsum[3])) *
                                     ((1.0f + COMMIT) / (float)NELEM));
    }
}

extern "C" void kernel_launch(void* const* d_in, const int* in_sizes, int n_in,
                              void* d_out, int out_size, void* d_ws,
                              size_t ws_size, hipStream_t stream) {
    const float* x = (const float*)d_in[0];    // [32,4096,64] f32
    const float* emb = (const float*)d_in[1];  // [1024,64] f32

    float* out = (float*)d_out;
    float* loss_slot = out;              // out[0]
    float* out_q = out + 1;              // out[1 .. 1+NELEM)
    float* idx_f = out + 1 + NELEM;      // indices as f32

    // workspace layout (16B-aligned slabs)
    float* enorm = (float*)d_ws;                                    // 4 KB
    unsigned short* e_hi = (unsigned short*)((char*)d_ws + 4096);   // 128 KB

    prep_emb_kernel<<<(K + 255) / 256, 256, 0, stream>>>(emb, enorm, e_hi,
                                                         loss_slot);
    argmin_kernel<<<NROWS / 64, 256, 0, stream>>>(x, emb, enorm, e_hi, out_q,
                                                  idx_f, loss_slot);
}